// Round 6
// baseline (266.599 us; speedup 1.0000x reference)
//
#include <hip/hip_runtime.h>
#include <hip/hip_bf16.h>

#define B_   128
#define T_   512
#define H_   512
#define V_   16
#define OUT_ 64
#define DH_  1024

// LDS: tab float4[V][H] (128K) + tsA float2[T] (4K) + vpk uchar[T] (512B)
#define TAB_BYTES (V_*H_*16)
#define TSA_BYTES (T_*8)
#define VPK_BYTES (T_)
#define SCAN_LDS  (TAB_BYTES + TSA_BYTES + VPK_BYTES)   // 135,680 B

__device__ __forceinline__ float bf2f(unsigned short u) {
    union { unsigned int i; float f; } x; x.i = ((unsigned int)u) << 16; return x.f;
}

// ---------------------------------------------------------------------------
// K1: bidirectional QRNN scan. grid (B,2), block 512 (thread=h).
// Clean 2-stage software pipeline (NO fused score): compute group k from
// register set A while group k+1's tab/ts LDS loads land in set B; the v-pack
// for group k+2 is fetched another stage ahead so tab addresses are ready.
// ---------------------------------------------------------------------------
__global__ __launch_bounds__(512) void qrnn_scan6(
    const float* __restrict__ x,    // (B,T,3)
    const float* __restrict__ emb,  // (V,10)
    const float* __restrict__ Wf, const float* __restrict__ bf_,
    const float* __restrict__ Wb, const float* __restrict__ bb_,
    __hip_bfloat16* __restrict__ hbuf)  // (B,T,DH)
{
    const int b = blockIdx.x, dir = blockIdx.y, h = threadIdx.x;
    const float* __restrict__ W    = dir ? Wb  : Wf;
    const float* __restrict__ bias = dir ? bb_ : bf_;

    extern __shared__ char smem[];
    float4*        tab = (float4*)smem;                       // [V][H]
    float2*        tsA = (float2*)(smem + TAB_BYTES);         // [T]
    unsigned char* vpk = (unsigned char*)(smem + TAB_BYTES + TSA_BYTES); // [T]

    {   // stage x: one thread per t
        const int t = h;
        const float* xp = x + ((size_t)b*T_ + t)*3;
        tsA[t] = make_float2(xp[0], xp[1]);
        vpk[t] = (unsigned char)(int)xp[2];
    }

    float w0[3], w1[3], wt[10][3];
#pragma unroll
    for (int g = 0; g < 3; ++g) {
        w0[g] = W[g*H_ + h];
        w1[g] = W[1536 + g*H_ + h];
#pragma unroll
        for (int e = 0; e < 10; ++e)
            wt[e][g] = W[(2+e)*1536 + g*H_ + h];
    }
    const float bz = bias[h], bfv = bias[H_+h], bov = bias[2*H_+h];

    const float FZ = -2.8853900817779268f;   // -2*log2(e)  (z gate / tanh)
    const float FF = -1.4426950408889634f;   // -log2(e)    (f,o gates)

#pragma unroll
    for (int v = 0; v < V_; ++v) {
        float a0 = bz, a1 = bfv, a2 = bov;
#pragma unroll
        for (int e = 0; e < 10; ++e) {
            const float ev = emb[v*10 + e];
            a0 = fmaf(ev, wt[e][0], a0);
            a1 = fmaf(ev, wt[e][1], a1);
            a2 = fmaf(ev, wt[e][2], a2);
        }
        tab[v*H_ + h] = make_float4(FZ*a0, FF*a1, FF*a2, 0.f);
    }
    const float w0z = FZ*w0[0], w0f = FF*w0[1], w0o = FF*w0[2];
    const float w1z = FZ*w1[0], w1f = FF*w1[1], w1o = FF*w1[2];
    __syncthreads();

    const float4* tsA4 = (const float4*)tsA;   // 2 steps per float4
    const uint2*  vp2  = (const uint2*)vpk;    // 8 steps per uint2

    float c = 0.f;
    __hip_bfloat16* hb = hbuf + (size_t)b*T_*DH_ + dir*H_ + h;

#define GIDX(i) (dir ? (63 - (i)) : (i))

#define SS(i, A0, A1, G) { \
    const float zp = fmaf(A0, w0z, fmaf(A1, w1z, (G).x)); \
    const float fp = fmaf(A0, w0f, fmaf(A1, w1f, (G).y)); \
    const float op = fmaf(A0, w0o, fmaf(A1, w1o, (G).z)); \
    const float rz = __builtin_amdgcn_rcpf(1.f + __builtin_amdgcn_exp2f(zp)); \
    const float f  = __builtin_amdgcn_rcpf(1.f + __builtin_amdgcn_exp2f(fp)); \
    const float o  = __builtin_amdgcn_rcpf(1.f + __builtin_amdgcn_exp2f(op)); \
    const float z  = fmaf(2.f, rz, -1.f); \
    c = fmaf(f, c - z, z); \
    const float hv = fmaxf(o * c, 0.f); \
    hb[(size_t)(t0 + (i))*DH_] = __float2bfloat16(hv); \
}

#define COMPUTE(K, T0_,T1_,T2_,T3_, G0,G1,G2,G3,G4,G5,G6,G7) { \
    const int t0 = (K)*8; \
    if (dir == 0) { \
        SS(0,T0_.x,T0_.y,G0) SS(1,T0_.z,T0_.w,G1) \
        SS(2,T1_.x,T1_.y,G2) SS(3,T1_.z,T1_.w,G3) \
        SS(4,T2_.x,T2_.y,G4) SS(5,T2_.z,T2_.w,G5) \
        SS(6,T3_.x,T3_.y,G6) SS(7,T3_.z,T3_.w,G7) \
    } else { \
        SS(7,T3_.z,T3_.w,G7) SS(6,T3_.x,T3_.y,G6) \
        SS(5,T2_.z,T2_.w,G5) SS(4,T2_.x,T2_.y,G4) \
        SS(3,T1_.z,T1_.w,G3) SS(2,T1_.x,T1_.y,G2) \
        SS(1,T0_.z,T0_.w,G1) SS(0,T0_.x,T0_.y,G0) \
    } \
}

#define TABRD(D0,D1,D2,D3,D4,D5,D6,D7, VP) \
    D0 = tab[(( (VP).x       ) & 255)*H_ + h]; \
    D1 = tab[(( (VP).x >>  8 ) & 255)*H_ + h]; \
    D2 = tab[(( (VP).x >> 16 ) & 255)*H_ + h]; \
    D3 = tab[(( (VP).x >> 24 )      )*H_ + h]; \
    D4 = tab[(( (VP).y       ) & 255)*H_ + h]; \
    D5 = tab[(( (VP).y >>  8 ) & 255)*H_ + h]; \
    D6 = tab[(( (VP).y >> 16 ) & 255)*H_ + h]; \
    D7 = tab[(( (VP).y >> 24 )      )*H_ + h];

    // prologue: group0 tab -> A; vp(group1) -> vpY
    const int k0 = GIDX(0), k1 = GIDX(1);
    uint2 vpP = vp2[k0];
    float4 tsE0 = tsA4[k0*4+0], tsE1 = tsA4[k0*4+1];
    float4 tsE2 = tsA4[k0*4+2], tsE3 = tsA4[k0*4+3];
    uint2 vpY = vp2[k1];
    float4 gA0,gA1,gA2,gA3,gA4,gA5,gA6,gA7;
    float4 gB0,gB1,gB2,gB3,gB4,gB5,gB6,gB7;
    float4 tsO0, tsO1, tsO2, tsO3;
    uint2 vpX;
    TABRD(gA0,gA1,gA2,gA3,gA4,gA5,gA6,gA7, vpP)

    for (int gi = 0; gi < 64; gi += 2) {
        {   // EVEN: prefetch gi+1 -> B (vp already in vpY); vp(gi+2) -> vpX
            const int iN1 = GIDX(gi+1);
            const int iN2 = GIDX(gi+2 <= 63 ? gi+2 : 63);
            vpX  = vp2[iN2];
            tsO0 = tsA4[iN1*4+0]; tsO1 = tsA4[iN1*4+1];
            tsO2 = tsA4[iN1*4+2]; tsO3 = tsA4[iN1*4+3];
            TABRD(gB0,gB1,gB2,gB3,gB4,gB5,gB6,gB7, vpY)
            COMPUTE(GIDX(gi), tsE0,tsE1,tsE2,tsE3, gA0,gA1,gA2,gA3,gA4,gA5,gA6,gA7)
        }
        {   // ODD: prefetch gi+2 -> A (from vpX); vp(gi+3) -> vpY
            const int iN2 = GIDX(gi+2 <= 63 ? gi+2 : 63);
            const int iN3 = GIDX(gi+3 <= 63 ? gi+3 : 63);
            vpY  = vp2[iN3];
            tsE0 = tsA4[iN2*4+0]; tsE1 = tsA4[iN2*4+1];
            tsE2 = tsA4[iN2*4+2]; tsE3 = tsA4[iN2*4+3];
            TABRD(gA0,gA1,gA2,gA3,gA4,gA5,gA6,gA7, vpX)
            COMPUTE(GIDX(gi+1), tsO0,tsO1,tsO2,tsO3, gB0,gB1,gB2,gB3,gB4,gB5,gB6,gB7)
        }
    }
#undef TABRD
#undef COMPUTE
#undef SS
#undef GIDX
}

// ---------------------------------------------------------------------------
// K2: s[b,t] = dot(hbuf[b,t,:], Mu). TWO rows per wave (interleaved loads for
// 2x memory-level parallelism; Mu registers shared). grid B*T/8, block 256.
// ---------------------------------------------------------------------------
__global__ __launch_bounds__(256) void score2b(
    const __hip_bfloat16* __restrict__ hbuf, const float* __restrict__ Mu,
    float* __restrict__ s)
{
    const int wid  = blockIdx.x*4 + (threadIdx.x >> 6);
    const int lane = threadIdx.x & 63;
    const int row0 = wid*2, row1 = row0 + 1;
    const uint4* hp0 = (const uint4*)(hbuf + (size_t)row0*DH_);
    const uint4* hp1 = (const uint4*)(hbuf + (size_t)row1*DH_);
    const float4* mp = (const float4*)Mu;
    float acc0 = 0.f, acc1 = 0.f;
#pragma unroll
    for (int k = 0; k < 2; ++k) {
        const int idx = k*64 + lane;
        const uint4 u0 = hp0[idx];
        const uint4 u1 = hp1[idx];
        const float4 m0 = mp[idx*2];
        const float4 m1 = mp[idx*2 + 1];
        acc0 = fmaf(bf2f((unsigned short)(u0.x & 0xffffu)), m0.x, acc0);
        acc0 = fmaf(bf2f((unsigned short)(u0.x >> 16)),     m0.y, acc0);
        acc0 = fmaf(bf2f((unsigned short)(u0.y & 0xffffu)), m0.z, acc0);
        acc0 = fmaf(bf2f((unsigned short)(u0.y >> 16)),     m0.w, acc0);
        acc0 = fmaf(bf2f((unsigned short)(u0.z & 0xffffu)), m1.x, acc0);
        acc0 = fmaf(bf2f((unsigned short)(u0.z >> 16)),     m1.y, acc0);
        acc0 = fmaf(bf2f((unsigned short)(u0.w & 0xffffu)), m1.z, acc0);
        acc0 = fmaf(bf2f((unsigned short)(u0.w >> 16)),     m1.w, acc0);
        acc1 = fmaf(bf2f((unsigned short)(u1.x & 0xffffu)), m0.x, acc1);
        acc1 = fmaf(bf2f((unsigned short)(u1.x >> 16)),     m0.y, acc1);
        acc1 = fmaf(bf2f((unsigned short)(u1.y & 0xffffu)), m0.z, acc1);
        acc1 = fmaf(bf2f((unsigned short)(u1.y >> 16)),     m0.w, acc1);
        acc1 = fmaf(bf2f((unsigned short)(u1.z & 0xffffu)), m1.x, acc1);
        acc1 = fmaf(bf2f((unsigned short)(u1.z >> 16)),     m1.y, acc1);
        acc1 = fmaf(bf2f((unsigned short)(u1.w & 0xffffu)), m1.z, acc1);
        acc1 = fmaf(bf2f((unsigned short)(u1.w >> 16)),     m1.w, acc1);
    }
#pragma unroll
    for (int off = 32; off; off >>= 1) {
        acc0 += __shfl_down(acc0, off);
        acc1 += __shfl_down(acc1, off);
    }
    if (lane == 0) { s[row0] = acc0; s[row1] = acc1; }
}

// ---------------------------------------------------------------------------
// K3: softmax over t per batch + zero ctx[b,:] for context4's atomics.
// grid B, block 512.
// ---------------------------------------------------------------------------
__global__ __launch_bounds__(512) void softmax_kernel(
    const float* __restrict__ s, float* __restrict__ w,
    float* __restrict__ ctx)
{
    const int b = blockIdx.x;
    const int t = threadIdx.x;
    const float v = s[b*T_ + t];

    // zero this batch's ctx row (context4 accumulates atomically)
    ctx[b*DH_ + t]       = 0.f;
    ctx[b*DH_ + 512 + t] = 0.f;

    __shared__ float redm[8];
    __shared__ float reds[8];

    float m = v;
#pragma unroll
    for (int off = 32; off; off >>= 1) m = fmaxf(m, __shfl_xor(m, off));
    if ((t & 63) == 0) redm[t >> 6] = m;
    __syncthreads();
    float mall = redm[0];
#pragma unroll
    for (int i = 1; i < 8; ++i) mall = fmaxf(mall, redm[i]);

    const float e = __expf(v - mall);
    float sum = e;
#pragma unroll
    for (int off = 32; off; off >>= 1) sum += __shfl_xor(sum, off);
    if ((t & 63) == 0) reds[t >> 6] = sum;
    __syncthreads();
    float sall = 0.f;
#pragma unroll
    for (int i = 0; i < 8; ++i) sall += reds[i];

    w[b*T_ + t] = e / sall;
}

// ---------------------------------------------------------------------------
// K4: context partial over a 64-t chunk. grid (B,8), block 256.
// Thread owns 8 d's (uint4 = 16B/lane); block processes 2 t's per iteration.
// ---------------------------------------------------------------------------
__global__ __launch_bounds__(256) void context4(
    const __hip_bfloat16* __restrict__ hbuf, const float* __restrict__ w,
    float* __restrict__ ctx)
{
    const int b = blockIdx.x, q = blockIdx.y;
    const int tsub = threadIdx.x >> 7;          // 0/1: which t of the pair
    const int d0   = (threadIdx.x & 127) * 8;

    __shared__ float ws[64];
    if (threadIdx.x < 64) ws[threadIdx.x] = w[b*T_ + q*64 + threadIdx.x];
    __syncthreads();

    const char* hp = (const char*)(hbuf + ((size_t)b*T_ + q*64 + tsub)*DH_ + d0);
    float a0=0.f,a1=0.f,a2=0.f,a3=0.f,a4=0.f,a5=0.f,a6=0.f,a7=0.f;
#pragma unroll 4
    for (int i = 0; i < 32; ++i) {
        const uint4 u = *(const uint4*)(hp + (size_t)i*2*(DH_*2));
        const float wv = ws[i*2 + tsub];
        a0 = fmaf(bf2f((unsigned short)(u.x & 0xffffu)), wv, a0);
        a1 = fmaf(bf2f((unsigned short)(u.x >> 16)),     wv, a1);
        a2 = fmaf(bf2f((unsigned short)(u.y & 0xffffu)), wv, a2);
        a3 = fmaf(bf2f((unsigned short)(u.y >> 16)),     wv, a3);
        a4 = fmaf(bf2f((unsigned short)(u.z & 0xffffu)), wv, a4);
        a5 = fmaf(bf2f((unsigned short)(u.z >> 16)),     wv, a5);
        a6 = fmaf(bf2f((unsigned short)(u.w & 0xffffu)), wv, a6);
        a7 = fmaf(bf2f((unsigned short)(u.w >> 16)),     wv, a7);
    }
    float* cp = ctx + b*DH_ + d0;
    atomicAdd(cp + 0, a0); atomicAdd(cp + 1, a1);
    atomicAdd(cp + 2, a2); atomicAdd(cp + 3, a3);
    atomicAdd(cp + 4, a4); atomicAdd(cp + 5, a5);
    atomicAdd(cp + 6, a6); atomicAdd(cp + 7, a7);
}

// ---------------------------------------------------------------------------
// K5: out[b,o] = dot(relu(ctx[b,:]), W_out[o,:]) + b_out[o]. One wave per (b,o).
// ---------------------------------------------------------------------------
__global__ __launch_bounds__(256) void out_kernel(
    const float* __restrict__ ctx, const float* __restrict__ Wout,
    const float* __restrict__ bout, float* __restrict__ out)
{
    const int idx  = blockIdx.x*4 + (threadIdx.x >> 6);  // b*64 + o
    const int lane = threadIdx.x & 63;
    const int b = idx >> 6;
    const int o = idx & 63;
    const float* cp = ctx + b*DH_;
    const float* wp = Wout + o*DH_;
    float acc = 0.f;
#pragma unroll
    for (int k = 0; k < DH_/64; ++k) {
        const int d = lane + k*64;
        acc = fmaf(fmaxf(cp[d], 0.f), wp[d], acc);
    }
#pragma unroll
    for (int off = 32; off; off >>= 1) acc += __shfl_down(acc, off);
    if (lane == 0) out[idx] = acc + bout[o];
}

// ---------------------------------------------------------------------------
extern "C" void kernel_launch(void* const* d_in, const int* in_sizes, int n_in,
                              void* d_out, int out_size, void* d_ws, size_t ws_size,
                              hipStream_t stream)
{
    const float* x    = (const float*)d_in[0];
    const float* emb  = (const float*)d_in[1];
    const float* Wf   = (const float*)d_in[2];
    const float* bf_  = (const float*)d_in[3];
    const float* Wb   = (const float*)d_in[4];
    const float* bb_  = (const float*)d_in[5];
    const float* Mu   = (const float*)d_in[6];
    const float* Wout = (const float*)d_in[7];
    const float* bout = (const float*)d_in[8];
    float* out = (float*)d_out;

    char* ws = (char*)d_ws;
    const size_t hbytes = (size_t)B_*T_*DH_*sizeof(__hip_bfloat16);  // 134.2 MB
    __hip_bfloat16* hbuf = (__hip_bfloat16*)ws;
    float* s   = (float*)(ws + hbytes);   // B*T
    float* w   = s + B_*T_;               // B*T
    float* ctx = w + B_*T_;               // B*DH

    (void)hipFuncSetAttribute((const void*)qrnn_scan6,
                              hipFuncAttributeMaxDynamicSharedMemorySize,
                              SCAN_LDS);

    qrnn_scan6<<<dim3(B_, 2), 512, SCAN_LDS, stream>>>(x, emb, Wf, bf_, Wb, bb_, hbuf);
    score2b<<<(B_*T_)/8, 256, 0, stream>>>(hbuf, Mu, s);
    softmax_kernel<<<B_, 512, 0, stream>>>(s, w, ctx);
    context4<<<dim3(B_, 8), 256, 0, stream>>>(hbuf, w, ctx);
    out_kernel<<<(B_*OUT_)/4, 256, 0, stream>>>(ctx, Wout, bout, out);
}

// Round 7
// 187.948 us; speedup vs baseline: 1.4185x; 1.4185x over previous
//
#include <hip/hip_runtime.h>
#include <hip/hip_bf16.h>

#define B_   128
#define T_   512
#define H_   512
#define V_   16
#define OUT_ 64
#define DH_  1024

// hbuf layout: [t][B_][DH_]  (t-major: concurrent blocks touch contiguous rows)

// LDS: tab float4[V][H] (128K) + tsA float2[T] (4K) + vpk uchar[T] (512B)
#define TAB_BYTES (V_*H_*16)
#define TSA_BYTES (T_*8)
#define VPK_BYTES (T_)
#define SCAN_LDS  (TAB_BYTES + TSA_BYTES + VPK_BYTES)   // 135,680 B

__device__ __forceinline__ float bf2f(unsigned short u) {
    union { unsigned int i; float f; } x; x.i = ((unsigned int)u) << 16; return x.f;
}
__device__ __forceinline__ float bf2f_lo(unsigned int u) {
    union { unsigned int i; float f; } x; x.i = u << 16; return x.f;
}
__device__ __forceinline__ float bf2f_hi(unsigned int u) {
    union { unsigned int i; float f; } x; x.i = u & 0xffff0000u; return x.f;
}

// ---------------------------------------------------------------------------
// K1: bidirectional QRNN scan (scan4 structure, t-major store).
// grid (B,2), block 512 (thread = h). Per 8-step group: 1 uint2 (8 v's) +
// 4 float4 ts reads + 8 INDEPENDENT tab b128 reads, then 8 register steps.
// ---------------------------------------------------------------------------
__global__ __launch_bounds__(512) void qrnn_scan7(
    const float* __restrict__ x,    // (B,T,3)
    const float* __restrict__ emb,  // (V,10)
    const float* __restrict__ Wf, const float* __restrict__ bf_,
    const float* __restrict__ Wb, const float* __restrict__ bb_,
    __hip_bfloat16* __restrict__ hbuf)  // (T,B,DH)
{
    const int b = blockIdx.x, dir = blockIdx.y, h = threadIdx.x;
    const float* __restrict__ W    = dir ? Wb  : Wf;
    const float* __restrict__ bias = dir ? bb_ : bf_;

    extern __shared__ char smem[];
    float4*        tab = (float4*)smem;                       // [V][H]
    float2*        tsA = (float2*)(smem + TAB_BYTES);         // [T]
    unsigned char* vpk = (unsigned char*)(smem + TAB_BYTES + TSA_BYTES); // [T]

    {   // stage x: one thread per t
        const int t = h;
        const float* xp = x + ((size_t)b*T_ + t)*3;
        tsA[t] = make_float2(xp[0], xp[1]);
        vpk[t] = (unsigned char)(int)xp[2];
    }

    float w0[3], w1[3], wt[10][3];
#pragma unroll
    for (int g = 0; g < 3; ++g) {
        w0[g] = W[g*H_ + h];
        w1[g] = W[1536 + g*H_ + h];
#pragma unroll
        for (int e = 0; e < 10; ++e)
            wt[e][g] = W[(2+e)*1536 + g*H_ + h];
    }
    const float bz = bias[h], bfv = bias[H_+h], bov = bias[2*H_+h];

    const float FZ = -2.8853900817779268f;   // -2*log2(e)  (z gate / tanh)
    const float FF = -1.4426950408889634f;   // -log2(e)    (f,o gates)

#pragma unroll
    for (int v = 0; v < V_; ++v) {
        float a0 = bz, a1 = bfv, a2 = bov;
#pragma unroll
        for (int e = 0; e < 10; ++e) {
            const float ev = emb[v*10 + e];
            a0 = fmaf(ev, wt[e][0], a0);
            a1 = fmaf(ev, wt[e][1], a1);
            a2 = fmaf(ev, wt[e][2], a2);
        }
        tab[v*H_ + h] = make_float4(FZ*a0, FF*a1, FF*a2, 0.f);
    }
    const float w0z = FZ*w0[0], w0f = FF*w0[1], w0o = FF*w0[2];
    const float w1z = FZ*w1[0], w1f = FF*w1[1], w1o = FF*w1[2];
    __syncthreads();

    const float4* tsA4 = (const float4*)tsA;   // 2 steps per float4
    const uint2*  vp2  = (const uint2*)vpk;    // 8 steps per uint2

    float c = 0.f;
    // t-major: row (t) base = t*B_*DH_; this thread's column = b*DH_+dir*H_+h
    __hip_bfloat16* hb = hbuf + (size_t)b*DH_ + dir*H_ + h;

#define SS(i, A0, A1, G) { \
    const float zp = fmaf(A0, w0z, fmaf(A1, w1z, (G).x)); \
    const float fp = fmaf(A0, w0f, fmaf(A1, w1f, (G).y)); \
    const float op = fmaf(A0, w0o, fmaf(A1, w1o, (G).z)); \
    const float rz = __builtin_amdgcn_rcpf(1.f + __builtin_amdgcn_exp2f(zp)); \
    const float f  = __builtin_amdgcn_rcpf(1.f + __builtin_amdgcn_exp2f(fp)); \
    const float o  = __builtin_amdgcn_rcpf(1.f + __builtin_amdgcn_exp2f(op)); \
    const float z  = fmaf(2.f, rz, -1.f); \
    c = fmaf(f, c - z, z); \
    const float hv = fmaxf(o * c, 0.f); \
    hb[(size_t)(t0 + (i))*(B_*DH_)] = __float2bfloat16(hv); \
}

#pragma unroll 2
    for (int gi = 0; gi < T_/8; ++gi) {
        const int gg = dir ? (T_/8 - 1 - gi) : gi;
        const int t0 = gg*8;
        const uint2  vp  = vp2[gg];
        const float4 tsa = tsA4[gg*4 + 0];
        const float4 tsb = tsA4[gg*4 + 1];
        const float4 tsc = tsA4[gg*4 + 2];
        const float4 tsd = tsA4[gg*4 + 3];
        const int v0 =  vp.x        & 255, v1 = (vp.x >> 8) & 255;
        const int v2 = (vp.x >> 16) & 255, v3 =  vp.x >> 24;
        const int v4 =  vp.y        & 255, v5 = (vp.y >> 8) & 255;
        const int v6 = (vp.y >> 16) & 255, v7 =  vp.y >> 24;
        const float4 g0 = tab[v0*H_ + h];
        const float4 g1 = tab[v1*H_ + h];
        const float4 g2 = tab[v2*H_ + h];
        const float4 g3 = tab[v3*H_ + h];
        const float4 g4 = tab[v4*H_ + h];
        const float4 g5 = tab[v5*H_ + h];
        const float4 g6 = tab[v6*H_ + h];
        const float4 g7 = tab[v7*H_ + h];
        if (dir == 0) {
            SS(0, tsa.x, tsa.y, g0) SS(1, tsa.z, tsa.w, g1)
            SS(2, tsb.x, tsb.y, g2) SS(3, tsb.z, tsb.w, g3)
            SS(4, tsc.x, tsc.y, g4) SS(5, tsc.z, tsc.w, g5)
            SS(6, tsd.x, tsd.y, g6) SS(7, tsd.z, tsd.w, g7)
        } else {
            SS(7, tsd.z, tsd.w, g7) SS(6, tsd.x, tsd.y, g6)
            SS(5, tsc.z, tsc.w, g5) SS(4, tsc.x, tsc.y, g4)
            SS(3, tsb.z, tsb.w, g3) SS(2, tsb.x, tsb.y, g2)
            SS(1, tsa.z, tsa.w, g1) SS(0, tsa.x, tsa.y, g0)
        }
    }
#undef SS
}

// ---------------------------------------------------------------------------
// K2: s[b,t] = dot(hbuf[t,b,:], Mu). Two rows per wave (MLP=4). grid B*T/8.
// Row r = t*B + b  ->  s[(r&127)*T + (r>>7)].
// ---------------------------------------------------------------------------
__global__ __launch_bounds__(256) void score7(
    const __hip_bfloat16* __restrict__ hbuf, const float* __restrict__ Mu,
    float* __restrict__ s)
{
    const int wid  = blockIdx.x*4 + (threadIdx.x >> 6);
    const int lane = threadIdx.x & 63;
    const int row0 = wid*2, row1 = row0 + 1;
    const uint4* hp0 = (const uint4*)(hbuf + (size_t)row0*DH_);
    const uint4* hp1 = (const uint4*)(hbuf + (size_t)row1*DH_);
    const float4* mp = (const float4*)Mu;
    float acc0 = 0.f, acc1 = 0.f;
#pragma unroll
    for (int k = 0; k < 2; ++k) {
        const int idx = k*64 + lane;
        const uint4 u0 = hp0[idx];
        const uint4 u1 = hp1[idx];
        const float4 m0 = mp[idx*2];
        const float4 m1 = mp[idx*2 + 1];
        acc0 = fmaf(bf2f_lo(u0.x), m0.x, acc0);
        acc0 = fmaf(bf2f_lo(u0.y), m0.z, acc0);
        acc0 = fmaf(bf2f_lo(u0.z), m1.x, acc0);
        acc0 = fmaf(bf2f_lo(u0.w), m1.z, acc0);
        acc0 = fmaf(bf2f_hi(u0.x), m0.y*65536.f, 0.f) + acc0;
        acc0 = fmaf(bf2f_hi(u0.y), 0.f, acc0);
        acc0 = acc0; // (placeholder removed below)
        acc1 = acc1;
    }
    // NOTE: replaced below by clean loop
    (void)acc0; (void)acc1;
    // clean implementation:
    float a0 = 0.f, a1 = 0.f;
#pragma unroll
    for (int k = 0; k < 2; ++k) {
        const int idx = k*64 + lane;
        const uint4 u0 = hp0[idx];
        const uint4 u1 = hp1[idx];
        const float4 m0 = mp[idx*2];
        const float4 m1 = mp[idx*2 + 1];
        a0 = fmaf(bf2f((unsigned short)(u0.x & 0xffffu)), m0.x, a0);
        a0 = fmaf(bf2f((unsigned short)(u0.x >> 16)),     m0.y, a0);
        a0 = fmaf(bf2f((unsigned short)(u0.y & 0xffffu)), m0.z, a0);
        a0 = fmaf(bf2f((unsigned short)(u0.y >> 16)),     m0.w, a0);
        a0 = fmaf(bf2f((unsigned short)(u0.z & 0xffffu)), m1.x, a0);
        a0 = fmaf(bf2f((unsigned short)(u0.z >> 16)),     m1.y, a0);
        a0 = fmaf(bf2f((unsigned short)(u0.w & 0xffffu)), m1.z, a0);
        a0 = fmaf(bf2f((unsigned short)(u0.w >> 16)),     m1.w, a0);
        a1 = fmaf(bf2f((unsigned short)(u1.x & 0xffffu)), m0.x, a1);
        a1 = fmaf(bf2f((unsigned short)(u1.x >> 16)),     m0.y, a1);
        a1 = fmaf(bf2f((unsigned short)(u1.y & 0xffffu)), m0.z, a1);
        a1 = fmaf(bf2f((unsigned short)(u1.y >> 16)),     m0.w, a1);
        a1 = fmaf(bf2f((unsigned short)(u1.z & 0xffffu)), m1.x, a1);
        a1 = fmaf(bf2f((unsigned short)(u1.z >> 16)),     m1.y, a1);
        a1 = fmaf(bf2f((unsigned short)(u1.w & 0xffffu)), m1.z, a1);
        a1 = fmaf(bf2f((unsigned short)(u1.w >> 16)),     m1.w, a1);
    }
#pragma unroll
    for (int off = 32; off; off >>= 1) {
        a0 += __shfl_down(a0, off);
        a1 += __shfl_down(a1, off);
    }
    if (lane == 0) {
        s[(row0 & (B_-1))*T_ + (row0 >> 7)] = a0;
        s[(row1 & (B_-1))*T_ + (row1 >> 7)] = a1;
    }
}

// ---------------------------------------------------------------------------
// K3: softmax over t per batch. grid B, block 512.
// ---------------------------------------------------------------------------
__global__ __launch_bounds__(512) void softmax_kernel(
    const float* __restrict__ s, float* __restrict__ w)
{
    const int b = blockIdx.x;
    const int t = threadIdx.x;
    const float v = s[b*T_ + t];

    __shared__ float redm[8];
    __shared__ float reds[8];

    float m = v;
#pragma unroll
    for (int off = 32; off; off >>= 1) m = fmaxf(m, __shfl_xor(m, off));
    if ((t & 63) == 0) redm[t >> 6] = m;
    __syncthreads();
    float mall = redm[0];
#pragma unroll
    for (int i = 1; i < 8; ++i) mall = fmaxf(mall, redm[i]);

    const float e = __expf(v - mall);
    float sum = e;
#pragma unroll
    for (int off = 32; off; off >>= 1) sum += __shfl_xor(sum, off);
    if ((t & 63) == 0) reds[t >> 6] = sum;
    __syncthreads();
    float sall = 0.f;
#pragma unroll
    for (int i = 0; i < 8; ++i) sall += reds[i];

    w[b*T_ + t] = e / sall;
}

// ---------------------------------------------------------------------------
// K4: context[b,d] = sum_t h[t,b,d]*w[b,t]. grid (B,2) [d-half], block 512.
// tsub = even/odd t; thread owns 2 d (4B load); 256-deep loop; LDS combine;
// direct ctx write (no atomics, no zero pass).
// ---------------------------------------------------------------------------
__global__ __launch_bounds__(512) void context7(
    const __hip_bfloat16* __restrict__ hbuf, const float* __restrict__ w,
    float* __restrict__ ctx)
{
    const int b    = blockIdx.x;
    const int dh   = blockIdx.y;               // d half 0/1
    const int tsub = threadIdx.x >> 8;         // 0/1 = even/odd t
    const int dloc = (threadIdx.x & 255) * 2;
    const int d0   = dh*512 + dloc;

    __shared__ float  ws[T_];                  // 2 KB
    __shared__ float2 pbuf[256];               // 2 KB

    ws[threadIdx.x] = w[b*T_ + threadIdx.x];
    __syncthreads();

    const char* hp = (const char*)hbuf + (((size_t)tsub*B_ + b)*DH_ + d0)*2;
    float a0 = 0.f, a1 = 0.f;
#pragma unroll 16
    for (int i = 0; i < 256; ++i) {
        const unsigned int u = *(const unsigned int*)(hp + (size_t)i*(2u*B_*DH_*2));
        const float wv = ws[i*2 + tsub];
        a0 = fmaf(bf2f_lo(u), wv, a0);
        a1 = fmaf(bf2f_hi(u), wv, a1);
    }
    if (tsub) pbuf[threadIdx.x & 255] = make_float2(a0, a1);
    __syncthreads();
    if (!tsub) {
        const float2 p = pbuf[threadIdx.x];
        *(float2*)(ctx + b*DH_ + d0) = make_float2(a0 + p.x, a1 + p.y);
    }
}

// ---------------------------------------------------------------------------
// K5: out[b,o] = dot(relu(ctx[b,:]), W_out[o,:]) + b_out[o]. One wave per (b,o).
// ---------------------------------------------------------------------------
__global__ __launch_bounds__(256) void out_kernel(
    const float* __restrict__ ctx, const float* __restrict__ Wout,
    const float* __restrict__ bout, float* __restrict__ out)
{
    const int idx  = blockIdx.x*4 + (threadIdx.x >> 6);  // b*64 + o
    const int lane = threadIdx.x & 63;
    const int b = idx >> 6;
    const int o = idx & 63;
    const float* cp = ctx + b*DH_;
    const float* wp = Wout + o*DH_;
    float acc = 0.f;
#pragma unroll
    for (int k = 0; k < DH_/64; ++k) {
        const int d = lane + k*64;
        acc = fmaf(fmaxf(cp[d], 0.f), wp[d], acc);
    }
#pragma unroll
    for (int off = 32; off; off >>= 1) acc += __shfl_down(acc, off);
    if (lane == 0) out[idx] = acc + bout[o];
}

// ---------------------------------------------------------------------------
extern "C" void kernel_launch(void* const* d_in, const int* in_sizes, int n_in,
                              void* d_out, int out_size, void* d_ws, size_t ws_size,
                              hipStream_t stream)
{
    const float* x    = (const float*)d_in[0];
    const float* emb  = (const float*)d_in[1];
    const float* Wf   = (const float*)d_in[2];
    const float* bf_  = (const float*)d_in[3];
    const float* Wb   = (const float*)d_in[4];
    const float* bb_  = (const float*)d_in[5];
    const float* Mu   = (const float*)d_in[6];
    const float* Wout = (const float*)d_in[7];
    const float* bout = (const float*)d_in[8];
    float* out = (float*)d_out;

    char* ws = (char*)d_ws;
    const size_t hbytes = (size_t)B_*T_*DH_*sizeof(__hip_bfloat16);  // 134.2 MB
    __hip_bfloat16* hbuf = (__hip_bfloat16*)ws;   // [T][B][DH]
    float* s   = (float*)(ws + hbytes);   // B*T
    float* w   = s + B_*T_;               // B*T
    float* ctx = w + B_*T_;               // B*DH

    (void)hipFuncSetAttribute((const void*)qrnn_scan7,
                              hipFuncAttributeMaxDynamicSharedMemorySize,
                              SCAN_LDS);

    qrnn_scan7<<<dim3(B_, 2), 512, SCAN_LDS, stream>>>(x, emb, Wf, bf_, Wb, bb_, hbuf);
    score7<<<(B_*T_)/8, 256, 0, stream>>>(hbuf, Mu, s);
    softmax_kernel<<<B_, 512, 0, stream>>>(s, w);
    context7<<<dim3(B_, 2), 512, 0, stream>>>(hbuf, w, ctx);
    out_kernel<<<(B_*OUT_)/4, 256, 0, stream>>>(ctx, Wout, bout, out);
}

// Round 8
// 172.023 us; speedup vs baseline: 1.5498x; 1.0926x over previous
//
#include <hip/hip_runtime.h>
#include <hip/hip_bf16.h>

#define B_   128
#define T_   512
#define H_   512
#define V_   16
#define OUT_ 64
#define DH_  1024

// hbuf layout: [t][B_][DH_]  (t-major)

// scan LDS: tab float4[V][H] (128K) + tsA float2[T] (4K) + vpk uchar[T] (512B)
#define TAB_BYTES (V_*H_*16)
#define TSA_BYTES (T_*8)
#define VPK_BYTES (T_)
#define SCAN_LDS  (TAB_BYTES + TSA_BYTES + VPK_BYTES)   // 135,680 B

#define LOG2E 1.4426950408889634f

__device__ __forceinline__ float bf2f_lo(unsigned int u) {
    union { unsigned int i; float f; } x; x.i = u << 16; return x.f;
}
__device__ __forceinline__ float bf2f_hi(unsigned int u) {
    union { unsigned int i; float f; } x; x.i = u & 0xffff0000u; return x.f;
}

// ---------------------------------------------------------------------------
// K1: bidirectional QRNN scan (scan7 structure + single-rcp gate algebra).
// grid (B,2), block 512 (thread = h). Per 8-step group: 1 uint2 (8 v's) +
// 4 float4 ts reads + 8 independent tab b128 reads, then 8 register steps.
// Per step: 3 exp2 + 1 rcp (was 3+3) — trans pipe is the measured bottleneck.
// ---------------------------------------------------------------------------
__global__ __launch_bounds__(512) void qrnn_scan8(
    const float* __restrict__ x,    // (B,T,3)
    const float* __restrict__ emb,  // (V,10)
    const float* __restrict__ Wf, const float* __restrict__ bf_,
    const float* __restrict__ Wb, const float* __restrict__ bb_,
    __hip_bfloat16* __restrict__ hbuf)  // (T,B,DH)
{
    const int b = blockIdx.x, dir = blockIdx.y, h = threadIdx.x;
    const float* __restrict__ W    = dir ? Wb  : Wf;
    const float* __restrict__ bias = dir ? bb_ : bf_;

    extern __shared__ char smem[];
    float4*        tab = (float4*)smem;                       // [V][H]
    float2*        tsA = (float2*)(smem + TAB_BYTES);         // [T]
    unsigned char* vpk = (unsigned char*)(smem + TAB_BYTES + TSA_BYTES); // [T]

    {   // stage x: one thread per t
        const int t = h;
        const float* xp = x + ((size_t)b*T_ + t)*3;
        tsA[t] = make_float2(xp[0], xp[1]);
        vpk[t] = (unsigned char)(int)xp[2];
    }

    float w0[3], w1[3], wt[10][3];
#pragma unroll
    for (int g = 0; g < 3; ++g) {
        w0[g] = W[g*H_ + h];
        w1[g] = W[1536 + g*H_ + h];
#pragma unroll
        for (int e = 0; e < 10; ++e)
            wt[e][g] = W[(2+e)*1536 + g*H_ + h];
    }
    const float bz = bias[h], bfv = bias[H_+h], bov = bias[2*H_+h];

    const float FZ = -2.8853900817779268f;   // -2*log2(e)  (z gate / tanh)
    const float FF = -1.4426950408889634f;   // -log2(e)    (f,o gates)

#pragma unroll
    for (int v = 0; v < V_; ++v) {
        float a0 = bz, a1 = bfv, a2 = bov;
#pragma unroll
        for (int e = 0; e < 10; ++e) {
            const float ev = emb[v*10 + e];
            a0 = fmaf(ev, wt[e][0], a0);
            a1 = fmaf(ev, wt[e][1], a1);
            a2 = fmaf(ev, wt[e][2], a2);
        }
        tab[v*H_ + h] = make_float4(FZ*a0, FF*a1, FF*a2, 0.f);
    }
    const float w0z = FZ*w0[0], w0f = FF*w0[1], w0o = FF*w0[2];
    const float w1z = FZ*w1[0], w1f = FF*w1[1], w1o = FF*w1[2];
    __syncthreads();

    const float4* tsA4 = (const float4*)tsA;   // 2 steps per float4
    const uint2*  vp2  = (const uint2*)vpk;    // 8 steps per uint2

    float c = 0.f;
    __hip_bfloat16* hb = hbuf + (size_t)b*DH_ + dir*H_ + h;

// single-rcp gates: A=1+e^-2az, B=1+e^-af, C=1+e^-ao; r=1/(ABC);
// tanh(az)=(2-A)*BC*r ; sigm(af)=AC*r ; sigm(ao)=AB*r
#define SS(i, A0, A1, G) { \
    const float zp = fmaf(A0, w0z, fmaf(A1, w1z, (G).x)); \
    const float fp = fmaf(A0, w0f, fmaf(A1, w1f, (G).y)); \
    const float op = fmaf(A0, w0o, fmaf(A1, w1o, (G).z)); \
    const float Az = 1.f + __builtin_amdgcn_exp2f(zp); \
    const float Bf = 1.f + __builtin_amdgcn_exp2f(fp); \
    const float Co = 1.f + __builtin_amdgcn_exp2f(op); \
    const float AB = Az*Bf, BC = Bf*Co, AC = Az*Co; \
    const float r  = __builtin_amdgcn_rcpf(AB*Co); \
    const float f  = AC*r; \
    const float og = AB*r; \
    const float z  = (2.f - Az)*(BC*r); \
    c = fmaf(f, c - z, z); \
    const float hv = fmaxf(og * c, 0.f); \
    hb[(size_t)(t0 + (i))*(B_*DH_)] = __float2bfloat16(hv); \
}

#pragma unroll 2
    for (int gi = 0; gi < T_/8; ++gi) {
        const int gg = dir ? (T_/8 - 1 - gi) : gi;
        const int t0 = gg*8;
        const uint2  vp  = vp2[gg];
        const float4 tsa = tsA4[gg*4 + 0];
        const float4 tsb = tsA4[gg*4 + 1];
        const float4 tsc = tsA4[gg*4 + 2];
        const float4 tsd = tsA4[gg*4 + 3];
        const int v0 =  vp.x        & 255, v1 = (vp.x >> 8) & 255;
        const int v2 = (vp.x >> 16) & 255, v3 =  vp.x >> 24;
        const int v4 =  vp.y        & 255, v5 = (vp.y >> 8) & 255;
        const int v6 = (vp.y >> 16) & 255, v7 =  vp.y >> 24;
        const float4 g0 = tab[v0*H_ + h];
        const float4 g1 = tab[v1*H_ + h];
        const float4 g2 = tab[v2*H_ + h];
        const float4 g3 = tab[v3*H_ + h];
        const float4 g4 = tab[v4*H_ + h];
        const float4 g5 = tab[v5*H_ + h];
        const float4 g6 = tab[v6*H_ + h];
        const float4 g7 = tab[v7*H_ + h];
        if (dir == 0) {
            SS(0, tsa.x, tsa.y, g0) SS(1, tsa.z, tsa.w, g1)
            SS(2, tsb.x, tsb.y, g2) SS(3, tsb.z, tsb.w, g3)
            SS(4, tsc.x, tsc.y, g4) SS(5, tsc.z, tsc.w, g5)
            SS(6, tsd.x, tsd.y, g6) SS(7, tsd.z, tsd.w, g7)
        } else {
            SS(7, tsd.z, tsd.w, g7) SS(6, tsd.x, tsd.y, g6)
            SS(5, tsc.z, tsc.w, g5) SS(4, tsc.x, tsc.y, g4)
            SS(3, tsb.z, tsb.w, g3) SS(2, tsb.x, tsb.y, g2)
            SS(1, tsa.z, tsa.w, g1) SS(0, tsa.x, tsa.y, g0)
        }
    }
#undef SS
}

// ---------------------------------------------------------------------------
// K2: fused score+softmax+context+output, ONE pass over hbuf.
// grid B (128 blocks), block 1024 (16 waves). Wave w owns t = j*16+w.
// No-max softmax (safe: h in [0,1), sum_t e^s <= 512*e^82 < FLT_MAX):
//   per t: s = dot(h_row, Mu) [wave-reduced]; e = exp(s); esum += e;
//   ctx_partial += e * h_row   (h reused from registers).
// Then: LDS combine of 16 wave partials -> relu -> 64-way output GEMV.
// ---------------------------------------------------------------------------
__global__ __launch_bounds__(1024) void postfuse(
    const __hip_bfloat16* __restrict__ hbuf,  // (T,B,DH)
    const float* __restrict__ Mu,             // (DH)
    const float* __restrict__ Wout,           // (OUT,DH)
    const float* __restrict__ bout,           // (OUT)
    float* __restrict__ out)                  // (B,OUT)
{
    const int b    = blockIdx.x;
    const int w    = threadIdx.x >> 6;    // 0..15
    const int lane = threadIdx.x & 63;

    __shared__ float pw[16][DH_];         // 64 KB wave-partial ctx
    __shared__ float psum[16];

    // lane's 16 Mu coefficients (d = k*512 + lane*8 + 0..7), loaded once
    float mu[16];
    const float4* mp = (const float4*)Mu;
#pragma unroll
    for (int k = 0; k < 2; ++k) {
        const float4 m0 = mp[(k*64 + lane)*2];
        const float4 m1 = mp[(k*64 + lane)*2 + 1];
        mu[k*8+0]=m0.x; mu[k*8+1]=m0.y; mu[k*8+2]=m0.z; mu[k*8+3]=m0.w;
        mu[k*8+4]=m1.x; mu[k*8+5]=m1.y; mu[k*8+6]=m1.z; mu[k*8+7]=m1.w;
    }

    float acc[16];
#pragma unroll
    for (int i = 0; i < 16; ++i) acc[i] = 0.f;
    float esum = 0.f;

    for (int j = 0; j < T_/16; ++j) {
        const int t = j*16 + w;
        const uint4* hp = (const uint4*)(hbuf + ((size_t)t*B_ + b)*DH_);
        const uint4 u0 = hp[lane];
        const uint4 u1 = hp[64 + lane];
        float hv[16];
        hv[0]  = bf2f_lo(u0.x); hv[1]  = bf2f_hi(u0.x);
        hv[2]  = bf2f_lo(u0.y); hv[3]  = bf2f_hi(u0.y);
        hv[4]  = bf2f_lo(u0.z); hv[5]  = bf2f_hi(u0.z);
        hv[6]  = bf2f_lo(u0.w); hv[7]  = bf2f_hi(u0.w);
        hv[8]  = bf2f_lo(u1.x); hv[9]  = bf2f_hi(u1.x);
        hv[10] = bf2f_lo(u1.y); hv[11] = bf2f_hi(u1.y);
        hv[12] = bf2f_lo(u1.z); hv[13] = bf2f_hi(u1.z);
        hv[14] = bf2f_lo(u1.w); hv[15] = bf2f_hi(u1.w);

        float s = 0.f;
#pragma unroll
        for (int i = 0; i < 16; ++i) s = fmaf(hv[i], mu[i], s);
#pragma unroll
        for (int off = 1; off <= 32; off <<= 1) s += __shfl_xor(s, off);

        const float e = __builtin_amdgcn_exp2f(s * LOG2E);
        esum += e;
#pragma unroll
        for (int i = 0; i < 16; ++i) acc[i] = fmaf(hv[i], e, acc[i]);
    }

    // write wave partials (d = k*512 + lane*8)
#pragma unroll
    for (int k = 0; k < 2; ++k) {
        *(float4*)&pw[w][k*512 + lane*8]     = make_float4(acc[k*8+0], acc[k*8+1], acc[k*8+2], acc[k*8+3]);
        *(float4*)&pw[w][k*512 + lane*8 + 4] = make_float4(acc[k*8+4], acc[k*8+5], acc[k*8+6], acc[k*8+7]);
    }
    if (lane == 0) psum[w] = esum;
    __syncthreads();

    // combine: thread d sums 16 partials; relu into pw[0][d]
    {
        const int d = threadIdx.x;
        float cs = 0.f;
#pragma unroll
        for (int i = 0; i < 16; ++i) cs += pw[i][d];
        pw[0][d] = fmaxf(cs, 0.f);
    }
    float rsum = 0.f;
#pragma unroll
    for (int i = 0; i < 16; ++i) rsum += psum[i];
    const float rinv = __builtin_amdgcn_rcpf(rsum);
    __syncthreads();

    // output GEMV: wave w -> outputs o = w*4 .. w*4+3
#pragma unroll
    for (int oo = 0; oo < 4; ++oo) {
        const int o = w*4 + oo;
        const float* wp = Wout + o*DH_;
        float a = 0.f;
#pragma unroll
        for (int k = 0; k < 16; ++k) {
            const int d = k*64 + lane;
            a = fmaf(pw[0][d], wp[d], a);
        }
#pragma unroll
        for (int off = 1; off <= 32; off <<= 1) a += __shfl_xor(a, off);
        if (lane == 0) out[b*OUT_ + o] = a*rinv + bout[o];
    }
}

// ---------------------------------------------------------------------------
extern "C" void kernel_launch(void* const* d_in, const int* in_sizes, int n_in,
                              void* d_out, int out_size, void* d_ws, size_t ws_size,
                              hipStream_t stream)
{
    const float* x    = (const float*)d_in[0];
    const float* emb  = (const float*)d_in[1];
    const float* Wf   = (const float*)d_in[2];
    const float* bf_  = (const float*)d_in[3];
    const float* Wb   = (const float*)d_in[4];
    const float* bb_  = (const float*)d_in[5];
    const float* Mu   = (const float*)d_in[6];
    const float* Wout = (const float*)d_in[7];
    const float* bout = (const float*)d_in[8];
    float* out = (float*)d_out;

    __hip_bfloat16* hbuf = (__hip_bfloat16*)d_ws;   // [T][B][DH], 134.2 MB

    (void)hipFuncSetAttribute((const void*)qrnn_scan8,
                              hipFuncAttributeMaxDynamicSharedMemorySize,
                              SCAN_LDS);

    qrnn_scan8<<<dim3(B_, 2), 512, SCAN_LDS, stream>>>(x, emb, Wf, bf_, Wb, bb_, hbuf);
    postfuse<<<B_, 1024, 0, stream>>>(hbuf, Mu, Wout, bout, out);
}

// Round 9
// 170.309 us; speedup vs baseline: 1.5654x; 1.0101x over previous
//
#include <hip/hip_runtime.h>
#include <hip/hip_bf16.h>

#define B_   128
#define T_   512
#define H_   512
#define V_   16
#define OUT_ 64
#define DH_  1024
#define NCH  8     // t-chunks for the fused epilogue

// hbuf layout: [t][B_][DH_]  (t-major)

// scan LDS: tab float4[V][H] (128K) + tsA float2[T] (4K) + vpk uchar[T] (512B)
#define TAB_BYTES (V_*H_*16)
#define TSA_BYTES (T_*8)
#define VPK_BYTES (T_)
#define SCAN_LDS  (TAB_BYTES + TSA_BYTES + VPK_BYTES)   // 135,680 B

#define LOG2E 1.4426950408889634f

__device__ __forceinline__ float bf2f_lo(unsigned int u) {
    union { unsigned int i; float f; } x; x.i = u << 16; return x.f;
}
__device__ __forceinline__ float bf2f_hi(unsigned int u) {
    union { unsigned int i; float f; } x; x.i = u & 0xffff0000u; return x.f;
}

// ---------------------------------------------------------------------------
// K1: bidirectional QRNN scan (scan7 structure/gates — proven 78.7 us).
// grid (B,2), block 512 (thread = h). Per 8-step group: 1 uint2 (8 v's) +
// 4 float4 ts reads + 8 independent tab b128 reads, then 8 register steps.
// ---------------------------------------------------------------------------
__global__ __launch_bounds__(512) void qrnn_scan9(
    const float* __restrict__ x,    // (B,T,3)
    const float* __restrict__ emb,  // (V,10)
    const float* __restrict__ Wf, const float* __restrict__ bf_,
    const float* __restrict__ Wb, const float* __restrict__ bb_,
    __hip_bfloat16* __restrict__ hbuf)  // (T,B,DH)
{
    const int b = blockIdx.x, dir = blockIdx.y, h = threadIdx.x;
    const float* __restrict__ W    = dir ? Wb  : Wf;
    const float* __restrict__ bias = dir ? bb_ : bf_;

    extern __shared__ char smem[];
    float4*        tab = (float4*)smem;                       // [V][H]
    float2*        tsA = (float2*)(smem + TAB_BYTES);         // [T]
    unsigned char* vpk = (unsigned char*)(smem + TAB_BYTES + TSA_BYTES); // [T]

    {   // stage x: one thread per t
        const int t = h;
        const float* xp = x + ((size_t)b*T_ + t)*3;
        tsA[t] = make_float2(xp[0], xp[1]);
        vpk[t] = (unsigned char)(int)xp[2];
    }

    float w0[3], w1[3], wt[10][3];
#pragma unroll
    for (int g = 0; g < 3; ++g) {
        w0[g] = W[g*H_ + h];
        w1[g] = W[1536 + g*H_ + h];
#pragma unroll
        for (int e = 0; e < 10; ++e)
            wt[e][g] = W[(2+e)*1536 + g*H_ + h];
    }
    const float bz = bias[h], bfv = bias[H_+h], bov = bias[2*H_+h];

    const float FZ = -2.8853900817779268f;   // -2*log2(e)  (z gate / tanh)
    const float FF = -1.4426950408889634f;   // -log2(e)    (f,o gates)

#pragma unroll
    for (int v = 0; v < V_; ++v) {
        float a0 = bz, a1 = bfv, a2 = bov;
#pragma unroll
        for (int e = 0; e < 10; ++e) {
            const float ev = emb[v*10 + e];
            a0 = fmaf(ev, wt[e][0], a0);
            a1 = fmaf(ev, wt[e][1], a1);
            a2 = fmaf(ev, wt[e][2], a2);
        }
        tab[v*H_ + h] = make_float4(FZ*a0, FF*a1, FF*a2, 0.f);
    }
    const float w0z = FZ*w0[0], w0f = FF*w0[1], w0o = FF*w0[2];
    const float w1z = FZ*w1[0], w1f = FF*w1[1], w1o = FF*w1[2];
    __syncthreads();

    const float4* tsA4 = (const float4*)tsA;   // 2 steps per float4
    const uint2*  vp2  = (const uint2*)vpk;    // 8 steps per uint2

    float c = 0.f;
    __hip_bfloat16* hb = hbuf + (size_t)b*DH_ + dir*H_ + h;

#define SS(i, A0, A1, G) { \
    const float zp = fmaf(A0, w0z, fmaf(A1, w1z, (G).x)); \
    const float fp = fmaf(A0, w0f, fmaf(A1, w1f, (G).y)); \
    const float op = fmaf(A0, w0o, fmaf(A1, w1o, (G).z)); \
    const float rz = __builtin_amdgcn_rcpf(1.f + __builtin_amdgcn_exp2f(zp)); \
    const float f  = __builtin_amdgcn_rcpf(1.f + __builtin_amdgcn_exp2f(fp)); \
    const float o  = __builtin_amdgcn_rcpf(1.f + __builtin_amdgcn_exp2f(op)); \
    const float z  = fmaf(2.f, rz, -1.f); \
    c = fmaf(f, c - z, z); \
    const float hv = fmaxf(o * c, 0.f); \
    hb[(size_t)(t0 + (i))*(B_*DH_)] = __float2bfloat16(hv); \
}

#pragma unroll 2
    for (int gi = 0; gi < T_/8; ++gi) {
        const int gg = dir ? (T_/8 - 1 - gi) : gi;
        const int t0 = gg*8;
        const uint2  vp  = vp2[gg];
        const float4 tsa = tsA4[gg*4 + 0];
        const float4 tsb = tsA4[gg*4 + 1];
        const float4 tsc = tsA4[gg*4 + 2];
        const float4 tsd = tsA4[gg*4 + 3];
        const int v0 =  vp.x        & 255, v1 = (vp.x >> 8) & 255;
        const int v2 = (vp.x >> 16) & 255, v3 =  vp.x >> 24;
        const int v4 =  vp.y        & 255, v5 = (vp.y >> 8) & 255;
        const int v6 = (vp.y >> 16) & 255, v7 =  vp.y >> 24;
        const float4 g0 = tab[v0*H_ + h];
        const float4 g1 = tab[v1*H_ + h];
        const float4 g2 = tab[v2*H_ + h];
        const float4 g3 = tab[v3*H_ + h];
        const float4 g4 = tab[v4*H_ + h];
        const float4 g5 = tab[v5*H_ + h];
        const float4 g6 = tab[v6*H_ + h];
        const float4 g7 = tab[v7*H_ + h];
        if (dir == 0) {
            SS(0, tsa.x, tsa.y, g0) SS(1, tsa.z, tsa.w, g1)
            SS(2, tsb.x, tsb.y, g2) SS(3, tsb.z, tsb.w, g3)
            SS(4, tsc.x, tsc.y, g4) SS(5, tsc.z, tsc.w, g5)
            SS(6, tsd.x, tsd.y, g6) SS(7, tsd.z, tsd.w, g7)
        } else {
            SS(7, tsd.z, tsd.w, g7) SS(6, tsd.x, tsd.y, g6)
            SS(5, tsc.z, tsc.w, g5) SS(4, tsc.x, tsc.y, g4)
            SS(3, tsb.z, tsb.w, g3) SS(2, tsb.x, tsb.y, g2)
            SS(1, tsa.z, tsa.w, g1) SS(0, tsa.x, tsa.y, g0)
        }
    }
#undef SS
}

// ---------------------------------------------------------------------------
// K2: fused score+exp+weighted-accumulate over a 64-t chunk (no-max softmax:
// partials are linear in t). grid (B, NCH) = 1024 blocks, block 512 (8 waves).
// Wave w owns rows t = q*64 + j*8 + w. Writes raw partial ctx + esum.
// ---------------------------------------------------------------------------
__global__ __launch_bounds__(512) void postfuse2(
    const __hip_bfloat16* __restrict__ hbuf,  // (T,B,DH)
    const float* __restrict__ Mu,             // (DH)
    float* __restrict__ pctx,                 // (B,NCH,DH) raw sums
    float* __restrict__ pesum)                // (B,NCH)
{
    const int b    = blockIdx.x;
    const int q    = blockIdx.y;
    const int w    = threadIdx.x >> 6;    // 0..7
    const int lane = threadIdx.x & 63;

    __shared__ float pw[8][DH_];          // 32 KB
    __shared__ float psum[8];

    // lane's 16 Mu coefficients (d = k*512 + lane*8 + 0..7)
    float mu[16];
    const float4* mp = (const float4*)Mu;
#pragma unroll
    for (int k = 0; k < 2; ++k) {
        const float4 m0 = mp[(k*64 + lane)*2];
        const float4 m1 = mp[(k*64 + lane)*2 + 1];
        mu[k*8+0]=m0.x; mu[k*8+1]=m0.y; mu[k*8+2]=m0.z; mu[k*8+3]=m0.w;
        mu[k*8+4]=m1.x; mu[k*8+5]=m1.y; mu[k*8+6]=m1.z; mu[k*8+7]=m1.w;
    }

    float acc[16];
#pragma unroll
    for (int i = 0; i < 16; ++i) acc[i] = 0.f;
    float esum = 0.f;

#pragma unroll 2
    for (int j = 0; j < 8; ++j) {
        const int t = q*64 + j*8 + w;
        const uint4* hp = (const uint4*)(hbuf + ((size_t)t*B_ + b)*DH_);
        const uint4 u0 = hp[lane];
        const uint4 u1 = hp[64 + lane];
        float hv[16];
        hv[0]  = bf2f_lo(u0.x); hv[1]  = bf2f_hi(u0.x);
        hv[2]  = bf2f_lo(u0.y); hv[3]  = bf2f_hi(u0.y);
        hv[4]  = bf2f_lo(u0.z); hv[5]  = bf2f_hi(u0.z);
        hv[6]  = bf2f_lo(u0.w); hv[7]  = bf2f_hi(u0.w);
        hv[8]  = bf2f_lo(u1.x); hv[9]  = bf2f_hi(u1.x);
        hv[10] = bf2f_lo(u1.y); hv[11] = bf2f_hi(u1.y);
        hv[12] = bf2f_lo(u1.z); hv[13] = bf2f_hi(u1.z);
        hv[14] = bf2f_lo(u1.w); hv[15] = bf2f_hi(u1.w);

        float s = 0.f;
#pragma unroll
        for (int i = 0; i < 16; ++i) s = fmaf(hv[i], mu[i], s);
#pragma unroll
        for (int off = 1; off <= 32; off <<= 1) s += __shfl_xor(s, off);

        const float e = __builtin_amdgcn_exp2f(s * LOG2E);
        esum += e;
#pragma unroll
        for (int i = 0; i < 16; ++i) acc[i] = fmaf(hv[i], e, acc[i]);
    }

#pragma unroll
    for (int k = 0; k < 2; ++k) {
        *(float4*)&pw[w][k*512 + lane*8]     = make_float4(acc[k*8+0], acc[k*8+1], acc[k*8+2], acc[k*8+3]);
        *(float4*)&pw[w][k*512 + lane*8 + 4] = make_float4(acc[k*8+4], acc[k*8+5], acc[k*8+6], acc[k*8+7]);
    }
    if (lane == 0) psum[w] = esum;
    __syncthreads();

    // column-sum the 8 wave partials; thread d covers d and d+512
    {
        const int d = threadIdx.x;
        float c0 = 0.f, c1 = 0.f;
#pragma unroll
        for (int i = 0; i < 8; ++i) { c0 += pw[i][d]; c1 += pw[i][d + 512]; }
        float* pc = pctx + ((size_t)b*NCH + q)*DH_;
        pc[d]       = c0;
        pc[d + 512] = c1;
    }
    if (threadIdx.x == 0) {
        float ts = 0.f;
#pragma unroll
        for (int i = 0; i < 8; ++i) ts += psum[i];
        pesum[b*NCH + q] = ts;
    }
}

// ---------------------------------------------------------------------------
// K3: combine partials -> relu -> normalized output GEMV. grid B, block 512.
// ---------------------------------------------------------------------------
__global__ __launch_bounds__(512) void combine_out(
    const float* __restrict__ pctx,   // (B,NCH,DH)
    const float* __restrict__ pesum,  // (B,NCH)
    const float* __restrict__ Wout,   // (OUT,DH)
    const float* __restrict__ bout,   // (OUT)
    float* __restrict__ out)          // (B,OUT)
{
    const int b    = blockIdx.x;
    const int w    = threadIdx.x >> 6;    // 0..7
    const int lane = threadIdx.x & 63;

    __shared__ float ctx[DH_];
    __shared__ float rinv_s;

    {
        const int d = threadIdx.x;
        const float* pc = pctx + (size_t)b*NCH*DH_;
        float c0 = 0.f, c1 = 0.f;
#pragma unroll
        for (int i = 0; i < NCH; ++i) { c0 += pc[i*DH_ + d]; c1 += pc[i*DH_ + d + 512]; }
        ctx[d]       = fmaxf(c0, 0.f);
        ctx[d + 512] = fmaxf(c1, 0.f);
    }
    if (threadIdx.x == 0) {
        float ts = 0.f;
#pragma unroll
        for (int i = 0; i < NCH; ++i) ts += pesum[b*NCH + i];
        rinv_s = __builtin_amdgcn_rcpf(ts);
    }
    __syncthreads();

    const float rinv = rinv_s;
#pragma unroll
    for (int oo = 0; oo < 8; ++oo) {
        const int o = w*8 + oo;
        const float* wp = Wout + o*DH_;
        float a = 0.f;
#pragma unroll
        for (int k = 0; k < 16; ++k) {
            const int d = k*64 + lane;
            a = fmaf(ctx[d], wp[d], a);
        }
#pragma unroll
        for (int off = 1; off <= 32; off <<= 1) a += __shfl_xor(a, off);
        if (lane == 0) out[b*OUT_ + o] = a*rinv + bout[o];
    }
}

// ---------------------------------------------------------------------------
extern "C" void kernel_launch(void* const* d_in, const int* in_sizes, int n_in,
                              void* d_out, int out_size, void* d_ws, size_t ws_size,
                              hipStream_t stream)
{
    const float* x    = (const float*)d_in[0];
    const float* emb  = (const float*)d_in[1];
    const float* Wf   = (const float*)d_in[2];
    const float* bf_  = (const float*)d_in[3];
    const float* Wb   = (const float*)d_in[4];
    const float* bb_  = (const float*)d_in[5];
    const float* Mu   = (const float*)d_in[6];
    const float* Wout = (const float*)d_in[7];
    const float* bout = (const float*)d_in[8];
    float* out = (float*)d_out;

    char* ws = (char*)d_ws;
    const size_t hbytes = (size_t)B_*T_*DH_*sizeof(__hip_bfloat16);  // 134.2 MB
    __hip_bfloat16* hbuf = (__hip_bfloat16*)ws;         // [T][B][DH]
    float* pctx  = (float*)(ws + hbytes);               // B*NCH*DH (4 MB)
    float* pesum = pctx + (size_t)B_*NCH*DH_;           // B*NCH

    (void)hipFuncSetAttribute((const void*)qrnn_scan9,
                              hipFuncAttributeMaxDynamicSharedMemorySize,
                              SCAN_LDS);

    qrnn_scan9<<<dim3(B_, 2), 512, SCAN_LDS, stream>>>(x, emb, Wf, bf_, Wb, bb_, hbuf);
    postfuse2<<<dim3(B_, NCH), 512, 0, stream>>>(hbuf, Mu, pctx, pesum);
    combine_out<<<B_, 512, 0, stream>>>(pctx, pesum, Wout, bout, out);
}